// Round 11
// baseline (454.339 us; speedup 1.0000x reference)
//
#include <hip/hip_runtime.h>
#include <hip/hip_bf16.h>
#include <float.h>
#include <math.h>

// ---------------------------------------------------------------------------
// 2-layer GAT (PyG GATConv semantics) on MI355X.
// v8: v7 + depth-1 software pipeline in layer1_agg (col+asrc for batch k+1
//     issued during phase B of batch k; the serial col->asrc->exp chain moves
//     off the critical path).
//   v7: register-prefetch pipeline in gemm1 (was lockstep, VALUBusy 37%).
// ---------------------------------------------------------------------------

#define LRELU(v) ((v) > 0.0f ? (v) : 0.2f * (v))

#define NB 64            // coarse bucket array size (49 used for N=50000)
#define BSHIFT 10        // bucket = dst >> BSHIFT
#define EPT 16           // edges per thread in bucket passes
#define EPB (256 * EPT)  // edges per block = 4096
#define SCHUNK 4096      // scan chunk (elements per block)
#define HWIN 3072        // LDS histogram window (dst slots)

__device__ inline void edge_sd(const int* __restrict__ ei, int E, int e,
                               int& s, int& d) {
  if (e < E) { s = ei[e]; d = ei[E + e]; }
  else       { s = e - E; d = e - E; }   // self-loops appended
}

// ---------------------------------------------------------------------------
// coarse per-bucket histogram, LDS-aggregated
// ---------------------------------------------------------------------------
__global__ __launch_bounds__(256) void coarse_hist_kernel(
    const int* __restrict__ ei, int E, int Et, int* __restrict__ ccnt) {
  __shared__ int lc[NB];
  int t = threadIdx.x;
  for (int i = t; i < NB; i += 256) lc[i] = 0;
  __syncthreads();
  size_t e0 = (size_t)blockIdx.x * EPB;
#pragma unroll
  for (int j = 0; j < EPT; ++j) {
    size_t e = e0 + (size_t)j * 256 + t;
    if (e < (size_t)Et) {
      int d = (e < (size_t)E) ? ei[E + e] : (int)(e - E);
      atomicAdd(&lc[d >> BSHIFT], 1);
    }
  }
  __syncthreads();
  for (int i = t; i < NB; i += 256)
    if (lc[i] > 0) atomicAdd(&ccnt[i], lc[i]);
}

// exclusive scan of <=64 values in one wave
__global__ __launch_bounds__(64) void scan64_kernel(
    const int* __restrict__ in, int* __restrict__ outp, int n) {
  int t = threadIdx.x;
  int v = (t < n) ? in[t] : 0;
  int incl = v;
#pragma unroll
  for (int off = 1; off < 64; off <<= 1) {
    int u = __shfl_up(incl, off);
    if (t >= off) incl += u;
  }
  if (t < n) outp[t] = incl - v;
}

// ---------------------------------------------------------------------------
// Phase 1: coarse bucket sort. rec = (dst<<16)|src  (N < 65536).
// ---------------------------------------------------------------------------
__global__ __launch_bounds__(256) void bucket_scatter_kernel(
    const int* __restrict__ ei, int E, int Et, int* __restrict__ gfill,
    unsigned int* __restrict__ coarse) {
  __shared__ int lcnt[NB];
  __shared__ int lbase[NB];
  int t = threadIdx.x;
  for (int i = t; i < NB; i += 256) lcnt[i] = 0;
  __syncthreads();

  unsigned int rec[EPT];
  int rank[EPT];
  size_t e0 = (size_t)blockIdx.x * EPB;
#pragma unroll
  for (int j = 0; j < EPT; ++j) {
    size_t e = e0 + (size_t)j * 256 + t;
    if (e < (size_t)Et) {
      int s, d; edge_sd(ei, E, (int)e, s, d);
      rec[j] = ((unsigned int)d << 16) | (unsigned int)s;
      rank[j] = atomicAdd(&lcnt[d >> BSHIFT], 1);
    } else {
      rec[j] = 0xFFFFFFFFu;
      rank[j] = 0;
    }
  }
  __syncthreads();
  for (int i = t; i < NB; i += 256)
    lbase[i] = (lcnt[i] > 0) ? atomicAdd(&gfill[i], lcnt[i]) : 0;
  __syncthreads();
#pragma unroll
  for (int j = 0; j < EPT; ++j) {
    if (rec[j] != 0xFFFFFFFFu) {
      int b = rec[j] >> (16 + BSHIFT);
      coarse[lbase[b] + rank[j]] = rec[j];
    }
  }
}

// ---------------------------------------------------------------------------
// Fine per-dst histogram over the bucket-sorted records (LDS window).
// ---------------------------------------------------------------------------
__global__ __launch_bounds__(256) void hist_coarse_kernel(
    const unsigned int* __restrict__ coarse, int Et,
    int* __restrict__ counts) {
  __shared__ int lh[HWIN];
  int t = threadIdx.x;
  size_t e0 = (size_t)blockIdx.x * EPB;
  if (e0 >= (size_t)Et) return;
  size_t e1 = e0 + EPB; if (e1 > (size_t)Et) e1 = (size_t)Et;
  int d0 = ((int)(coarse[e0] >> 16)) & ~((1 << BSHIFT) - 1);  // window base
  for (int i = t; i < HWIN; i += 256) lh[i] = 0;
  __syncthreads();
  for (size_t e = e0 + t; e < e1; e += 256) {
    int d = (int)(coarse[e] >> 16);
    int w = d - d0;
    if ((unsigned)w < HWIN) atomicAdd(&lh[w], 1);
    else atomicAdd(&counts[d], 1);   // rare fallback
  }
  __syncthreads();
  for (int i = t; i < HWIN; i += 256)
    if (lh[i] > 0) atomicAdd(&counts[d0 + i], lh[i]);
}

// ---------------------------------------------------------------------------
// Hierarchical scan: blocksum -> scan64(bsum) -> final (rowptr[0..N] + fill)
// ---------------------------------------------------------------------------
__global__ __launch_bounds__(256) void scan_blocksum_kernel(
    const int* __restrict__ counts, int* __restrict__ bsum, int N) {
  __shared__ int tsum[256];
  int t = threadIdx.x;
  int base = blockIdx.x * SCHUNK;
  int sum = 0;
  for (int i = t; i < SCHUNK; i += 256) {
    int idx = base + i;
    if (idx < N) sum += counts[idx];
  }
  tsum[t] = sum;
  __syncthreads();
  for (int off = 128; off > 0; off >>= 1) {
    if (t < off) tsum[t] += tsum[t + off];
    __syncthreads();
  }
  if (t == 0) bsum[blockIdx.x] = tsum[0];
}

__global__ __launch_bounds__(256) void scan_final_kernel(
    const int* __restrict__ counts, const int* __restrict__ boff,
    int* __restrict__ rowptr, int* __restrict__ fill, int N) {
  __shared__ int lds[SCHUNK];
  __shared__ int tsum[256];
  int t = threadIdx.x;
  int base = blockIdx.x * SCHUNK;
  for (int i = t; i < SCHUNK; i += 256) {
    int idx = base + i;
    lds[i] = (idx < N) ? counts[idx] : 0;
  }
  __syncthreads();
  int lo = t * 16;
  int s = 0;
#pragma unroll
  for (int j = 0; j < 16; ++j) s += lds[lo + j];
  tsum[t] = s;
  __syncthreads();
  for (int off = 1; off < 256; off <<= 1) {
    int v = (t >= off) ? tsum[t - off] : 0;
    __syncthreads();
    tsum[t] += v;
    __syncthreads();
  }
  int run = boff[blockIdx.x] + tsum[t] - s;  // exclusive prefix
#pragma unroll
  for (int j = 0; j < 16; ++j) {
    int idx = base + lo + j;
    if (idx <= N) rowptr[idx] = run;
    if (idx < N) fill[idx] = run;
    run += lds[lo + j];
  }
}

// ---------------------------------------------------------------------------
// Phase 2: fine scatter from bucket-ordered records (L2-resident windows).
// ---------------------------------------------------------------------------
__global__ __launch_bounds__(256) void fine_scatter_kernel(
    const unsigned int* __restrict__ coarse, int Et, int* __restrict__ fill,
    int* __restrict__ colsrc) {
  int nwg = gridDim.x;
  int q = nwg >> 3, r = nwg & 7;
  int xcd = blockIdx.x & 7, li = blockIdx.x >> 3;
  int wg = (xcd < r ? xcd * (q + 1) : r * (q + 1) + (xcd - r) * q) + li;
  int t = threadIdx.x;
  size_t e0 = (size_t)wg * EPB;
#pragma unroll
  for (int j = 0; j < EPT; ++j) {
    size_t e = e0 + (size_t)j * 256 + t;
    if (e < (size_t)Et) {
      unsigned int rec = coarse[e];
      int d = rec >> 16, s = rec & 0xFFFF;
      int pos = atomicAdd(&fill[d], 1);
      colsrc[pos] = s;
    }
  }
}

// ---------------------------------------------------------------------------
// h1[N,64] = x[N,512] @ W1[512,64], alpha logits fused in the epilogue.
// v7: register-prefetch pipeline — per k0: {ds_write staged regs, sync,
// issue global loads of tile k0+64 into regs, compute, sync}.
// ---------------------------------------------------------------------------
__global__ __launch_bounds__(256) void gemm1_kernel(
    const float* __restrict__ x, const float* __restrict__ W,
    const float* __restrict__ a_src, const float* __restrict__ a_dst,
    float* __restrict__ h1, float* __restrict__ asrc,
    float* __restrict__ adst, int N) {
  __shared__ float xs[64][68];
  __shared__ float Wt[64][64];
  const int t = threadIdx.x;
  const int tx = t & 15;
  const int ty = t >> 4;
  const int row0 = blockIdx.x * 64;

  const float* sx[4];
#pragma unroll
  for (int j = 0; j < 4; ++j) {
    int f = j * 256 + t;
    int rr = row0 + (f >> 4); if (rr >= N) rr = N - 1;
    sx[j] = x + (size_t)rr * 512 + (f & 15) * 4;
  }

  float4 px[4], pw[4];
#pragma unroll
  for (int j = 0; j < 4; ++j) {
    int f = j * 256 + t;
    px[j] = *(const float4*)(sx[j]);
    pw[j] = *(const float4*)(W + (size_t)(f >> 4) * 64 + (f & 15) * 4);
  }

  float acc[4][4] = {};

  for (int k0 = 0; k0 < 512; k0 += 64) {
#pragma unroll
    for (int j = 0; j < 4; ++j) {
      int f = j * 256 + t;
      *(float4*)&xs[f >> 4][(f & 15) * 4] = px[j];
      *(float4*)&Wt[f >> 4][(f & 15) * 4] = pw[j];
    }
    __syncthreads();

    if (k0 + 64 < 512) {
#pragma unroll
      for (int j = 0; j < 4; ++j) {
        int f = j * 256 + t;
        px[j] = *(const float4*)(sx[j] + k0 + 64);
        pw[j] = *(const float4*)(W + (size_t)(k0 + 64 + (f >> 4)) * 64 +
                                 (f & 15) * 4);
      }
    }

#pragma unroll 8
    for (int kk = 0; kk < 64; ++kk) {
      float a0 = xs[ty * 4 + 0][kk];
      float a1 = xs[ty * 4 + 1][kk];
      float a2 = xs[ty * 4 + 2][kk];
      float a3 = xs[ty * 4 + 3][kk];
      float4 b = *(const float4*)&Wt[kk][tx * 4];
      acc[0][0] = fmaf(a0, b.x, acc[0][0]);
      acc[0][1] = fmaf(a0, b.y, acc[0][1]);
      acc[0][2] = fmaf(a0, b.z, acc[0][2]);
      acc[0][3] = fmaf(a0, b.w, acc[0][3]);
      acc[1][0] = fmaf(a1, b.x, acc[1][0]);
      acc[1][1] = fmaf(a1, b.y, acc[1][1]);
      acc[1][2] = fmaf(a1, b.z, acc[1][2]);
      acc[1][3] = fmaf(a1, b.w, acc[1][3]);
      acc[2][0] = fmaf(a2, b.x, acc[2][0]);
      acc[2][1] = fmaf(a2, b.y, acc[2][1]);
      acc[2][2] = fmaf(a2, b.z, acc[2][2]);
      acc[2][3] = fmaf(a2, b.w, acc[2][3]);
      acc[3][0] = fmaf(a3, b.x, acc[3][0]);
      acc[3][1] = fmaf(a3, b.y, acc[3][1]);
      acc[3][2] = fmaf(a3, b.z, acc[3][2]);
      acc[3][3] = fmaf(a3, b.w, acc[3][3]);
    }
    __syncthreads();
  }

  // h1 store
#pragma unroll
  for (int r = 0; r < 4; ++r) {
    int rr = row0 + ty * 4 + r;
    if (rr < N) {
      float4 v = make_float4(acc[r][0], acc[r][1], acc[r][2], acc[r][3]);
      *(float4*)(h1 + (size_t)rr * 64 + tx * 4) = v;
    }
  }

  // fused alpha logits
  const int h = tx >> 1;
  const int half = (tx & 1) * 4;
  float4 as = *(const float4*)(a_src + h * 8 + half);
  float4 ad = *(const float4*)(a_dst + h * 8 + half);
#pragma unroll
  for (int r = 0; r < 4; ++r) {
    float ps = acc[r][0] * as.x + acc[r][1] * as.y +
               acc[r][2] * as.z + acc[r][3] * as.w;
    float pd = acc[r][0] * ad.x + acc[r][1] * ad.y +
               acc[r][2] * ad.z + acc[r][3] * ad.w;
    ps += __shfl_xor(ps, 1);
    pd += __shfl_xor(pd, 1);
    int rr = row0 + ty * 4 + r;
    if ((tx & 1) == 0 && rr < N) {
      asrc[(size_t)rr * 8 + h] = ps;
      adst[(size_t)rr * 8 + h] = pd;
    }
  }
}

// ---------------------------------------------------------------------------
// Layer-1 aggregation over CSR. One wave per dst node; 64 lanes = 64 output
// features (head h = l>>3). Batch-8 with depth-1 pipeline: col+asrc for
// batch k+1 are issued before phase B of batch k, so the serial
// col->asrc->exp chain hides under the 8 h1 gathers + fmas.
// ---------------------------------------------------------------------------
__global__ __launch_bounds__(256) void layer1_agg_kernel(
    const int* __restrict__ rowptr, const int* __restrict__ col,
    const float* __restrict__ asrc, const float* __restrict__ adst,
    const float* __restrict__ h1, const float* __restrict__ b1,
    float* __restrict__ out1, int N) {
  int wave = (blockIdx.x * 256 + threadIdx.x) >> 6;
  int l = threadIdx.x & 63;
  if (wave >= N) return;
  int n = wave;
  int h = l >> 3;      // head (both mappings)
  int e8 = l & 7;      // edge slot (phase-A mapping)
  int hbase = l & 56;  // h*8
  float adh = adst[(size_t)n * 8 + h];
  int k0 = rowptr[n], k1 = rowptr[n + 1];
  float acc = 0.f, den = 0.f;

  // prologue: load batch 0's col + asrc
  int idx0 = k0 + e8;
  int sp = col[idx0 < k1 ? idx0 : k1 - 1];
  float av = asrc[(size_t)sp * 8 + h];

  for (int kb = k0; kb < k1; kb += 8) {
    bool ok = kb + e8 < k1;
    float pv = ok ? __expf(LRELU(av + adh)) : 0.f;
    den += pv;

    // prefetch next batch's col + asrc (hides under phase B)
    int spn = sp; float avn = av;
    if (kb + 8 < k1) {
      int idx = kb + 8 + e8;
      spn = col[idx < k1 ? idx : k1 - 1];
      avn = asrc[(size_t)spn * 8 + h];
    }

#pragma unroll
    for (int j = 0; j < 8; ++j) {
      int s = __shfl(sp, j);
      float p = __shfl(pv, hbase | j);
      acc = fmaf(p, h1[(size_t)s * 64 + l], acc);
    }
    sp = spn; av = avn;
  }

  den += __shfl_xor(den, 1);
  den += __shfl_xor(den, 2);
  den += __shfl_xor(den, 4);

  float v = acc / den + b1[l];
  out1[(size_t)n * 64 + l] = v > 0.f ? v : expm1f(v);  // ELU
}

// ---------------------------------------------------------------------------
// h2[N,10] = h[N,64] @ W2[64,10]; also alpha logits for layer 2 (H=1).
// ---------------------------------------------------------------------------
__global__ __launch_bounds__(256) void layer2_node_kernel(
    const float* __restrict__ h, const float* __restrict__ W2,
    const float* __restrict__ a2s, const float* __restrict__ a2d,
    float* __restrict__ h2, float* __restrict__ asrc2,
    float* __restrict__ adst2, int N) {
  __shared__ float Wt[640];
  __shared__ float sas[10], sad[10];
  int t = threadIdx.x;
  for (int i = t; i < 640; i += 256) Wt[i] = W2[i];
  if (t < 10) { sas[t] = a2s[t]; sad[t] = a2d[t]; }
  __syncthreads();
  int n = blockIdx.x * 256 + t;
  if (n >= N) return;
  float hr[64];
  const float4* hp = (const float4*)(h + (size_t)n * 64);
#pragma unroll
  for (int i = 0; i < 16; ++i) ((float4*)hr)[i] = hp[i];
  float o[10] = {};
#pragma unroll 8
  for (int k = 0; k < 64; ++k) {
    float hv = hr[k];
#pragma unroll
    for (int c = 0; c < 10; ++c) o[c] = fmaf(hv, Wt[k * 10 + c], o[c]);
  }
  float vs = 0.f, vd = 0.f;
#pragma unroll
  for (int c = 0; c < 10; ++c) {
    h2[(size_t)n * 10 + c] = o[c];
    vs = fmaf(o[c], sas[c], vs);
    vd = fmaf(o[c], sad[c], vd);
  }
  asrc2[n] = vs;
  adst2[n] = vd;
}

// ---------------------------------------------------------------------------
// Layer-2 aggregation over CSR, fused with +b2 and log_softmax -> out.
// ---------------------------------------------------------------------------
__global__ __launch_bounds__(256) void layer2_agg_kernel(
    const int* __restrict__ rowptr, const int* __restrict__ col,
    const float* __restrict__ asrc, const float* __restrict__ adst,
    const float* __restrict__ h2, const float* __restrict__ b2,
    float* __restrict__ out, int N) {
  int idx = blockIdx.x * 256 + threadIdx.x;
  int n = idx >> 3, sub = idx & 7;
  if (n >= N) return;
  float adh = adst[n];
  int k0 = rowptr[n], k1 = rowptr[n + 1];
  float o[10] = {};
  float den = 0.f;
  for (int k = k0 + sub; k < k1; k += 8) {
    int s = col[k];
    float e = LRELU(asrc[s] + adh);
    float p = __expf(e);
    den += p;
    const float2* hp = (const float2*)(h2 + (size_t)s * 10);
    float2 a = hp[0], b = hp[1], c = hp[2], d = hp[3], f = hp[4];
    o[0] += p * a.x; o[1] += p * a.y;
    o[2] += p * b.x; o[3] += p * b.y;
    o[4] += p * c.x; o[5] += p * c.y;
    o[6] += p * d.x; o[7] += p * d.y;
    o[8] += p * f.x; o[9] += p * f.y;
  }
#pragma unroll
  for (int m = 1; m < 8; m <<= 1) {
    den += __shfl_xor(den, m);
#pragma unroll
    for (int c = 0; c < 10; ++c) o[c] += __shfl_xor(o[c], m);
  }
  if (sub == 0) {
    float v[10], mx = -FLT_MAX;
#pragma unroll
    for (int c = 0; c < 10; ++c) {
      v[c] = o[c] / den + b2[c];
      mx = fmaxf(mx, v[c]);
    }
    float sum = 0.f;
#pragma unroll
    for (int c = 0; c < 10; ++c) sum += __expf(v[c] - mx);
    float lg = logf(sum);
#pragma unroll
    for (int c = 0; c < 10; ++c) out[(size_t)n * 10 + c] = v[c] - mx - lg;
  }
}

// ---------------------------------------------------------------------------
extern "C" void kernel_launch(void* const* d_in, const int* in_sizes, int n_in,
                              void* d_out, int out_size, void* d_ws,
                              size_t ws_size, hipStream_t stream) {
  const float* x   = (const float*)d_in[0];
  const int*   ei  = (const int*)d_in[1];
  const float* W1  = (const float*)d_in[2];
  const float* a1s = (const float*)d_in[3];
  const float* a1d = (const float*)d_in[4];
  const float* b1  = (const float*)d_in[5];
  const float* W2  = (const float*)d_in[6];
  const float* a2s = (const float*)d_in[7];
  const float* a2d = (const float*)d_in[8];
  const float* b2  = (const float*)d_in[9];
  float* out = (float*)d_out;

  const int F = 512;
  const int N = in_sizes[0] / F;        // 50000
  const int E = in_sizes[1] / 2;        // 1600000
  const int Et = E + N;                 // + self loops

  // workspace layout
  char* wsb = (char*)d_ws;
  size_t o = 0;
  auto alloc = [&](size_t bytes) {
    void* p = wsb + o;
    o += (bytes + 255) & ~(size_t)255;
    return p;
  };
  float* h1     = (float*)alloc((size_t)N * 64 * 4);
  float* out1   = (float*)alloc((size_t)N * 64 * 4);
  float* asrc1  = (float*)alloc((size_t)N * 8 * 4);
  float* adst1  = (float*)alloc((size_t)N * 8 * 4);
  float* h2     = (float*)alloc((size_t)N * 10 * 4);
  float* asrc2  = (float*)alloc((size_t)N * 4);
  float* adst2  = (float*)alloc((size_t)N * 4);
  int*   counts = (int*)alloc((size_t)N * 4);
  int*   rowptr = (int*)alloc((size_t)(N + 1) * 4);
  int*   fill   = (int*)alloc((size_t)N * 4);
  int*   colsrc = (int*)alloc((size_t)Et * 4);
  unsigned int* coarse = (unsigned int*)alloc((size_t)Et * 4);
  int*   ccnt   = (int*)alloc((size_t)NB * 4);
  int*   gfill  = (int*)alloc((size_t)NB * 4);
  int*   bsum   = (int*)alloc((size_t)64 * 4);
  int*   boff   = (int*)alloc((size_t)64 * 4);

  const int nblk_e = (Et + EPB - 1) / EPB;           // 4096-edge chunks
  const int nblk_s = (N + SCHUNK) / SCHUNK;          // covers N+1 entries

  // ---- CSR build (shared by both layers) ----
  hipMemsetAsync(counts, 0, (size_t)N * 4, stream);
  hipMemsetAsync(ccnt, 0, (size_t)NB * 4, stream);
  coarse_hist_kernel<<<nblk_e, 256, 0, stream>>>(ei, E, Et, ccnt);
  scan64_kernel<<<1, 64, 0, stream>>>(ccnt, gfill, NB);
  bucket_scatter_kernel<<<nblk_e, 256, 0, stream>>>(ei, E, Et, gfill, coarse);
  hist_coarse_kernel<<<nblk_e, 256, 0, stream>>>(coarse, Et, counts);
  scan_blocksum_kernel<<<nblk_s, 256, 0, stream>>>(counts, bsum, N);
  scan64_kernel<<<1, 64, 0, stream>>>(bsum, boff, nblk_s);
  scan_final_kernel<<<nblk_s, 256, 0, stream>>>(counts, boff, rowptr, fill, N);
  fine_scatter_kernel<<<nblk_e, 256, 0, stream>>>(coarse, Et, fill, colsrc);

  // ---- layer 1 (gemm + fused alpha) ----
  gemm1_kernel<<<(N + 63) / 64, 256, 0, stream>>>(x, W1, a1s, a1d, h1,
                                                  asrc1, adst1, N);
  layer1_agg_kernel<<<(N * 64 + 255) / 256, 256, 0, stream>>>(
      rowptr, colsrc, asrc1, adst1, h1, b1, out1, N);

  // ---- layer 2 ----
  layer2_node_kernel<<<(N + 255) / 256, 256, 0, stream>>>(out1, W2, a2s, a2d,
                                                          h2, asrc2, adst2, N);
  layer2_agg_kernel<<<(N * 8 + 255) / 256, 256, 0, stream>>>(
      rowptr, colsrc, asrc2, adst2, h2, b2, out, N);
}

// Round 12
// 413.515 us; speedup vs baseline: 1.0987x; 1.0987x over previous
//
#include <hip/hip_runtime.h>
#include <hip/hip_bf16.h>
#include <float.h>
#include <math.h>

// ---------------------------------------------------------------------------
// 2-layer GAT (PyG GATConv semantics) on MI355X.
// v9: gemm1 reverted to v6.1 (v7's register-prefetch spilled to scratch:
//     VGPR allocator pinned 64 regs, px/pw went to scratch -> WRITE_SIZE
//     15.6->188MB, gemm1 69->118us). layer1_agg keeps v8's depth-1 pipeline.
// ---------------------------------------------------------------------------

#define LRELU(v) ((v) > 0.0f ? (v) : 0.2f * (v))

#define NB 64            // coarse bucket array size (49 used for N=50000)
#define BSHIFT 10        // bucket = dst >> BSHIFT
#define EPT 16           // edges per thread in bucket passes
#define EPB (256 * EPT)  // edges per block = 4096
#define SCHUNK 4096      // scan chunk (elements per block)
#define HWIN 3072        // LDS histogram window (dst slots)

__device__ inline void edge_sd(const int* __restrict__ ei, int E, int e,
                               int& s, int& d) {
  if (e < E) { s = ei[e]; d = ei[E + e]; }
  else       { s = e - E; d = e - E; }   // self-loops appended
}

// ---------------------------------------------------------------------------
// coarse per-bucket histogram, LDS-aggregated
// ---------------------------------------------------------------------------
__global__ __launch_bounds__(256) void coarse_hist_kernel(
    const int* __restrict__ ei, int E, int Et, int* __restrict__ ccnt) {
  __shared__ int lc[NB];
  int t = threadIdx.x;
  for (int i = t; i < NB; i += 256) lc[i] = 0;
  __syncthreads();
  size_t e0 = (size_t)blockIdx.x * EPB;
#pragma unroll
  for (int j = 0; j < EPT; ++j) {
    size_t e = e0 + (size_t)j * 256 + t;
    if (e < (size_t)Et) {
      int d = (e < (size_t)E) ? ei[E + e] : (int)(e - E);
      atomicAdd(&lc[d >> BSHIFT], 1);
    }
  }
  __syncthreads();
  for (int i = t; i < NB; i += 256)
    if (lc[i] > 0) atomicAdd(&ccnt[i], lc[i]);
}

// exclusive scan of <=64 values in one wave
__global__ __launch_bounds__(64) void scan64_kernel(
    const int* __restrict__ in, int* __restrict__ outp, int n) {
  int t = threadIdx.x;
  int v = (t < n) ? in[t] : 0;
  int incl = v;
#pragma unroll
  for (int off = 1; off < 64; off <<= 1) {
    int u = __shfl_up(incl, off);
    if (t >= off) incl += u;
  }
  if (t < n) outp[t] = incl - v;
}

// ---------------------------------------------------------------------------
// Phase 1: coarse bucket sort. rec = (dst<<16)|src  (N < 65536).
// ---------------------------------------------------------------------------
__global__ __launch_bounds__(256) void bucket_scatter_kernel(
    const int* __restrict__ ei, int E, int Et, int* __restrict__ gfill,
    unsigned int* __restrict__ coarse) {
  __shared__ int lcnt[NB];
  __shared__ int lbase[NB];
  int t = threadIdx.x;
  for (int i = t; i < NB; i += 256) lcnt[i] = 0;
  __syncthreads();

  unsigned int rec[EPT];
  int rank[EPT];
  size_t e0 = (size_t)blockIdx.x * EPB;
#pragma unroll
  for (int j = 0; j < EPT; ++j) {
    size_t e = e0 + (size_t)j * 256 + t;
    if (e < (size_t)Et) {
      int s, d; edge_sd(ei, E, (int)e, s, d);
      rec[j] = ((unsigned int)d << 16) | (unsigned int)s;
      rank[j] = atomicAdd(&lcnt[d >> BSHIFT], 1);
    } else {
      rec[j] = 0xFFFFFFFFu;
      rank[j] = 0;
    }
  }
  __syncthreads();
  for (int i = t; i < NB; i += 256)
    lbase[i] = (lcnt[i] > 0) ? atomicAdd(&gfill[i], lcnt[i]) : 0;
  __syncthreads();
#pragma unroll
  for (int j = 0; j < EPT; ++j) {
    if (rec[j] != 0xFFFFFFFFu) {
      int b = rec[j] >> (16 + BSHIFT);
      coarse[lbase[b] + rank[j]] = rec[j];
    }
  }
}

// ---------------------------------------------------------------------------
// Fine per-dst histogram over the bucket-sorted records (LDS window).
// ---------------------------------------------------------------------------
__global__ __launch_bounds__(256) void hist_coarse_kernel(
    const unsigned int* __restrict__ coarse, int Et,
    int* __restrict__ counts) {
  __shared__ int lh[HWIN];
  int t = threadIdx.x;
  size_t e0 = (size_t)blockIdx.x * EPB;
  if (e0 >= (size_t)Et) return;
  size_t e1 = e0 + EPB; if (e1 > (size_t)Et) e1 = (size_t)Et;
  int d0 = ((int)(coarse[e0] >> 16)) & ~((1 << BSHIFT) - 1);  // window base
  for (int i = t; i < HWIN; i += 256) lh[i] = 0;
  __syncthreads();
  for (size_t e = e0 + t; e < e1; e += 256) {
    int d = (int)(coarse[e] >> 16);
    int w = d - d0;
    if ((unsigned)w < HWIN) atomicAdd(&lh[w], 1);
    else atomicAdd(&counts[d], 1);   // rare fallback
  }
  __syncthreads();
  for (int i = t; i < HWIN; i += 256)
    if (lh[i] > 0) atomicAdd(&counts[d0 + i], lh[i]);
}

// ---------------------------------------------------------------------------
// Hierarchical scan: blocksum -> scan64(bsum) -> final (rowptr[0..N] + fill)
// ---------------------------------------------------------------------------
__global__ __launch_bounds__(256) void scan_blocksum_kernel(
    const int* __restrict__ counts, int* __restrict__ bsum, int N) {
  __shared__ int tsum[256];
  int t = threadIdx.x;
  int base = blockIdx.x * SCHUNK;
  int sum = 0;
  for (int i = t; i < SCHUNK; i += 256) {
    int idx = base + i;
    if (idx < N) sum += counts[idx];
  }
  tsum[t] = sum;
  __syncthreads();
  for (int off = 128; off > 0; off >>= 1) {
    if (t < off) tsum[t] += tsum[t + off];
    __syncthreads();
  }
  if (t == 0) bsum[blockIdx.x] = tsum[0];
}

__global__ __launch_bounds__(256) void scan_final_kernel(
    const int* __restrict__ counts, const int* __restrict__ boff,
    int* __restrict__ rowptr, int* __restrict__ fill, int N) {
  __shared__ int lds[SCHUNK];
  __shared__ int tsum[256];
  int t = threadIdx.x;
  int base = blockIdx.x * SCHUNK;
  for (int i = t; i < SCHUNK; i += 256) {
    int idx = base + i;
    lds[i] = (idx < N) ? counts[idx] : 0;
  }
  __syncthreads();
  int lo = t * 16;
  int s = 0;
#pragma unroll
  for (int j = 0; j < 16; ++j) s += lds[lo + j];
  tsum[t] = s;
  __syncthreads();
  for (int off = 1; off < 256; off <<= 1) {
    int v = (t >= off) ? tsum[t - off] : 0;
    __syncthreads();
    tsum[t] += v;
    __syncthreads();
  }
  int run = boff[blockIdx.x] + tsum[t] - s;  // exclusive prefix
#pragma unroll
  for (int j = 0; j < 16; ++j) {
    int idx = base + lo + j;
    if (idx <= N) rowptr[idx] = run;
    if (idx < N) fill[idx] = run;
    run += lds[lo + j];
  }
}

// ---------------------------------------------------------------------------
// Phase 2: fine scatter from bucket-ordered records (L2-resident windows).
// ---------------------------------------------------------------------------
__global__ __launch_bounds__(256) void fine_scatter_kernel(
    const unsigned int* __restrict__ coarse, int Et, int* __restrict__ fill,
    int* __restrict__ colsrc) {
  int nwg = gridDim.x;
  int q = nwg >> 3, r = nwg & 7;
  int xcd = blockIdx.x & 7, li = blockIdx.x >> 3;
  int wg = (xcd < r ? xcd * (q + 1) : r * (q + 1) + (xcd - r) * q) + li;
  int t = threadIdx.x;
  size_t e0 = (size_t)wg * EPB;
#pragma unroll
  for (int j = 0; j < EPT; ++j) {
    size_t e = e0 + (size_t)j * 256 + t;
    if (e < (size_t)Et) {
      unsigned int rec = coarse[e];
      int d = rec >> 16, s = rec & 0xFFFF;
      int pos = atomicAdd(&fill[d], 1);
      colsrc[pos] = s;
    }
  }
}

// ---------------------------------------------------------------------------
// h1[N,64] = x[N,512] @ W1[512,64], alpha logits fused in the epilogue.
// (v6.1 version, measured 69us — no register prefetch; v7's spilled.)
// ---------------------------------------------------------------------------
__global__ __launch_bounds__(256) void gemm1_kernel(
    const float* __restrict__ x, const float* __restrict__ W,
    const float* __restrict__ a_src, const float* __restrict__ a_dst,
    float* __restrict__ h1, float* __restrict__ asrc,
    float* __restrict__ adst, int N) {
  __shared__ float xs[64][68];
  __shared__ float Wt[64][64];
  const int t = threadIdx.x;
  const int tx = t & 15;
  const int ty = t >> 4;
  const int row0 = blockIdx.x * 64;

  float acc[4][4] = {};

  for (int k0 = 0; k0 < 512; k0 += 64) {
#pragma unroll
    for (int p = 0; p < 4; ++p) {
      int r = p * 16 + ty;
      int rr = row0 + r; if (rr >= N) rr = N - 1;
      *(float4*)&xs[r][tx * 4] =
          *(const float4*)(x + (size_t)rr * 512 + k0 + tx * 4);
      *(float4*)&Wt[r][tx * 4] =
          *(const float4*)(W + (size_t)(k0 + r) * 64 + tx * 4);
    }
    __syncthreads();

#pragma unroll 8
    for (int kk = 0; kk < 64; ++kk) {
      float a0 = xs[ty * 4 + 0][kk];
      float a1 = xs[ty * 4 + 1][kk];
      float a2 = xs[ty * 4 + 2][kk];
      float a3 = xs[ty * 4 + 3][kk];
      float4 b = *(const float4*)&Wt[kk][tx * 4];
      acc[0][0] = fmaf(a0, b.x, acc[0][0]);
      acc[0][1] = fmaf(a0, b.y, acc[0][1]);
      acc[0][2] = fmaf(a0, b.z, acc[0][2]);
      acc[0][3] = fmaf(a0, b.w, acc[0][3]);
      acc[1][0] = fmaf(a1, b.x, acc[1][0]);
      acc[1][1] = fmaf(a1, b.y, acc[1][1]);
      acc[1][2] = fmaf(a1, b.z, acc[1][2]);
      acc[1][3] = fmaf(a1, b.w, acc[1][3]);
      acc[2][0] = fmaf(a2, b.x, acc[2][0]);
      acc[2][1] = fmaf(a2, b.y, acc[2][1]);
      acc[2][2] = fmaf(a2, b.z, acc[2][2]);
      acc[2][3] = fmaf(a2, b.w, acc[2][3]);
      acc[3][0] = fmaf(a3, b.x, acc[3][0]);
      acc[3][1] = fmaf(a3, b.y, acc[3][1]);
      acc[3][2] = fmaf(a3, b.z, acc[3][2]);
      acc[3][3] = fmaf(a3, b.w, acc[3][3]);
    }
    __syncthreads();
  }

  // h1 store
#pragma unroll
  for (int r = 0; r < 4; ++r) {
    int rr = row0 + ty * 4 + r;
    if (rr < N) {
      float4 v = make_float4(acc[r][0], acc[r][1], acc[r][2], acc[r][3]);
      *(float4*)(h1 + (size_t)rr * 64 + tx * 4) = v;
    }
  }

  // fused alpha logits
  const int h = tx >> 1;
  const int half = (tx & 1) * 4;
  float4 as = *(const float4*)(a_src + h * 8 + half);
  float4 ad = *(const float4*)(a_dst + h * 8 + half);
#pragma unroll
  for (int r = 0; r < 4; ++r) {
    float ps = acc[r][0] * as.x + acc[r][1] * as.y +
               acc[r][2] * as.z + acc[r][3] * as.w;
    float pd = acc[r][0] * ad.x + acc[r][1] * ad.y +
               acc[r][2] * ad.z + acc[r][3] * ad.w;
    ps += __shfl_xor(ps, 1);
    pd += __shfl_xor(pd, 1);
    int rr = row0 + ty * 4 + r;
    if ((tx & 1) == 0 && rr < N) {
      asrc[(size_t)rr * 8 + h] = ps;
      adst[(size_t)rr * 8 + h] = pd;
    }
  }
}

// ---------------------------------------------------------------------------
// Layer-1 aggregation over CSR. One wave per dst node; 64 lanes = 64 output
// features (head h = l>>3). Batch-8 with depth-1 pipeline: col+asrc for
// batch k+1 are issued before phase B of batch k.
// ---------------------------------------------------------------------------
__global__ __launch_bounds__(256) void layer1_agg_kernel(
    const int* __restrict__ rowptr, const int* __restrict__ col,
    const float* __restrict__ asrc, const float* __restrict__ adst,
    const float* __restrict__ h1, const float* __restrict__ b1,
    float* __restrict__ out1, int N) {
  int wave = (blockIdx.x * 256 + threadIdx.x) >> 6;
  int l = threadIdx.x & 63;
  if (wave >= N) return;
  int n = wave;
  int h = l >> 3;      // head (both mappings)
  int e8 = l & 7;      // edge slot (phase-A mapping)
  int hbase = l & 56;  // h*8
  float adh = adst[(size_t)n * 8 + h];
  int k0 = rowptr[n], k1 = rowptr[n + 1];
  float acc = 0.f, den = 0.f;

  // prologue: load batch 0's col + asrc
  int idx0 = k0 + e8;
  int sp = col[idx0 < k1 ? idx0 : k1 - 1];
  float av = asrc[(size_t)sp * 8 + h];

  for (int kb = k0; kb < k1; kb += 8) {
    bool ok = kb + e8 < k1;
    float pv = ok ? __expf(LRELU(av + adh)) : 0.f;
    den += pv;

    // prefetch next batch's col + asrc (hides under phase B)
    int spn = sp; float avn = av;
    if (kb + 8 < k1) {
      int idx = kb + 8 + e8;
      spn = col[idx < k1 ? idx : k1 - 1];
      avn = asrc[(size_t)spn * 8 + h];
    }

#pragma unroll
    for (int j = 0; j < 8; ++j) {
      int s = __shfl(sp, j);
      float p = __shfl(pv, hbase | j);
      acc = fmaf(p, h1[(size_t)s * 64 + l], acc);
    }
    sp = spn; av = avn;
  }

  den += __shfl_xor(den, 1);
  den += __shfl_xor(den, 2);
  den += __shfl_xor(den, 4);

  float v = acc / den + b1[l];
  out1[(size_t)n * 64 + l] = v > 0.f ? v : expm1f(v);  // ELU
}

// ---------------------------------------------------------------------------
// h2[N,10] = h[N,64] @ W2[64,10]; also alpha logits for layer 2 (H=1).
// ---------------------------------------------------------------------------
__global__ __launch_bounds__(256) void layer2_node_kernel(
    const float* __restrict__ h, const float* __restrict__ W2,
    const float* __restrict__ a2s, const float* __restrict__ a2d,
    float* __restrict__ h2, float* __restrict__ asrc2,
    float* __restrict__ adst2, int N) {
  __shared__ float Wt[640];
  __shared__ float sas[10], sad[10];
  int t = threadIdx.x;
  for (int i = t; i < 640; i += 256) Wt[i] = W2[i];
  if (t < 10) { sas[t] = a2s[t]; sad[t] = a2d[t]; }
  __syncthreads();
  int n = blockIdx.x * 256 + t;
  if (n >= N) return;
  float hr[64];
  const float4* hp = (const float4*)(h + (size_t)n * 64);
#pragma unroll
  for (int i = 0; i < 16; ++i) ((float4*)hr)[i] = hp[i];
  float o[10] = {};
#pragma unroll 8
  for (int k = 0; k < 64; ++k) {
    float hv = hr[k];
#pragma unroll
    for (int c = 0; c < 10; ++c) o[c] = fmaf(hv, Wt[k * 10 + c], o[c]);
  }
  float vs = 0.f, vd = 0.f;
#pragma unroll
  for (int c = 0; c < 10; ++c) {
    h2[(size_t)n * 10 + c] = o[c];
    vs = fmaf(o[c], sas[c], vs);
    vd = fmaf(o[c], sad[c], vd);
  }
  asrc2[n] = vs;
  adst2[n] = vd;
}

// ---------------------------------------------------------------------------
// Layer-2 aggregation over CSR, fused with +b2 and log_softmax -> out.
// ---------------------------------------------------------------------------
__global__ __launch_bounds__(256) void layer2_agg_kernel(
    const int* __restrict__ rowptr, const int* __restrict__ col,
    const float* __restrict__ asrc, const float* __restrict__ adst,
    const float* __restrict__ h2, const float* __restrict__ b2,
    float* __restrict__ out, int N) {
  int idx = blockIdx.x * 256 + threadIdx.x;
  int n = idx >> 3, sub = idx & 7;
  if (n >= N) return;
  float adh = adst[n];
  int k0 = rowptr[n], k1 = rowptr[n + 1];
  float o[10] = {};
  float den = 0.f;
  for (int k = k0 + sub; k < k1; k += 8) {
    int s = col[k];
    float e = LRELU(asrc[s] + adh);
    float p = __expf(e);
    den += p;
    const float2* hp = (const float2*)(h2 + (size_t)s * 10);
    float2 a = hp[0], b = hp[1], c = hp[2], d = hp[3], f = hp[4];
    o[0] += p * a.x; o[1] += p * a.y;
    o[2] += p * b.x; o[3] += p * b.y;
    o[4] += p * c.x; o[5] += p * c.y;
    o[6] += p * d.x; o[7] += p * d.y;
    o[8] += p * f.x; o[9] += p * f.y;
  }
#pragma unroll
  for (int m = 1; m < 8; m <<= 1) {
    den += __shfl_xor(den, m);
#pragma unroll
    for (int c = 0; c < 10; ++c) o[c] += __shfl_xor(o[c], m);
  }
  if (sub == 0) {
    float v[10], mx = -FLT_MAX;
#pragma unroll
    for (int c = 0; c < 10; ++c) {
      v[c] = o[c] / den + b2[c];
      mx = fmaxf(mx, v[c]);
    }
    float sum = 0.f;
#pragma unroll
    for (int c = 0; c < 10; ++c) sum += __expf(v[c] - mx);
    float lg = logf(sum);
#pragma unroll
    for (int c = 0; c < 10; ++c) out[(size_t)n * 10 + c] = v[c] - mx - lg;
  }
}

// ---------------------------------------------------------------------------
extern "C" void kernel_launch(void* const* d_in, const int* in_sizes, int n_in,
                              void* d_out, int out_size, void* d_ws,
                              size_t ws_size, hipStream_t stream) {
  const float* x   = (const float*)d_in[0];
  const int*   ei  = (const int*)d_in[1];
  const float* W1  = (const float*)d_in[2];
  const float* a1s = (const float*)d_in[3];
  const float* a1d = (const float*)d_in[4];
  const float* b1  = (const float*)d_in[5];
  const float* W2  = (const float*)d_in[6];
  const float* a2s = (const float*)d_in[7];
  const float* a2d = (const float*)d_in[8];
  const float* b2  = (const float*)d_in[9];
  float* out = (float*)d_out;

  const int F = 512;
  const int N = in_sizes[0] / F;        // 50000
  const int E = in_sizes[1] / 2;        // 1600000
  const int Et = E + N;                 // + self loops

  // workspace layout
  char* wsb = (char*)d_ws;
  size_t o = 0;
  auto alloc = [&](size_t bytes) {
    void* p = wsb + o;
    o += (bytes + 255) & ~(size_t)255;
    return p;
  };
  float* h1     = (float*)alloc((size_t)N * 64 * 4);
  float* out1   = (float*)alloc((size_t)N * 64 * 4);
  float* asrc1  = (float*)alloc((size_t)N * 8 * 4);
  float* adst1  = (float*)alloc((size_t)N * 8 * 4);
  float* h2     = (float*)alloc((size_t)N * 10 * 4);
  float* asrc2  = (float*)alloc((size_t)N * 4);
  float* adst2  = (float*)alloc((size_t)N * 4);
  int*   counts = (int*)alloc((size_t)N * 4);
  int*   rowptr = (int*)alloc((size_t)(N + 1) * 4);
  int*   fill   = (int*)alloc((size_t)N * 4);
  int*   colsrc = (int*)alloc((size_t)Et * 4);
  unsigned int* coarse = (unsigned int*)alloc((size_t)Et * 4);
  int*   ccnt   = (int*)alloc((size_t)NB * 4);
  int*   gfill  = (int*)alloc((size_t)NB * 4);
  int*   bsum   = (int*)alloc((size_t)64 * 4);
  int*   boff   = (int*)alloc((size_t)64 * 4);

  const int nblk_e = (Et + EPB - 1) / EPB;           // 4096-edge chunks
  const int nblk_s = (N + SCHUNK) / SCHUNK;          // covers N+1 entries

  // ---- CSR build (shared by both layers) ----
  hipMemsetAsync(counts, 0, (size_t)N * 4, stream);
  hipMemsetAsync(ccnt, 0, (size_t)NB * 4, stream);
  coarse_hist_kernel<<<nblk_e, 256, 0, stream>>>(ei, E, Et, ccnt);
  scan64_kernel<<<1, 64, 0, stream>>>(ccnt, gfill, NB);
  bucket_scatter_kernel<<<nblk_e, 256, 0, stream>>>(ei, E, Et, gfill, coarse);
  hist_coarse_kernel<<<nblk_e, 256, 0, stream>>>(coarse, Et, counts);
  scan_blocksum_kernel<<<nblk_s, 256, 0, stream>>>(counts, bsum, N);
  scan64_kernel<<<1, 64, 0, stream>>>(bsum, boff, nblk_s);
  scan_final_kernel<<<nblk_s, 256, 0, stream>>>(counts, boff, rowptr, fill, N);
  fine_scatter_kernel<<<nblk_e, 256, 0, stream>>>(coarse, Et, fill, colsrc);

  // ---- layer 1 (gemm + fused alpha) ----
  gemm1_kernel<<<(N + 63) / 64, 256, 0, stream>>>(x, W1, a1s, a1d, h1,
                                                  asrc1, adst1, N);
  layer1_agg_kernel<<<(N * 64 + 255) / 256, 256, 0, stream>>>(
      rowptr, colsrc, asrc1, adst1, h1, b1, out1, N);

  // ---- layer 2 ----
  layer2_node_kernel<<<(N + 255) / 256, 256, 0, stream>>>(out1, W2, a2s, a2d,
                                                          h2, asrc2, adst2, N);
  layer2_agg_kernel<<<(N * 8 + 255) / 256, 256, 0, stream>>>(
      rowptr, colsrc, asrc2, adst2, h2, b2, out, N);
}